// Round 1
// baseline (232.987 us; speedup 1.0000x reference)
//
#include <hip/hip_runtime.h>
#include <hip/hip_bf16.h>
#include <stdint.h>

#define NUM_TOKENS 8192
#define HIDDEN 1024
#define NEXP 8
#define TOPK 2

typedef __bf16 bf16;
typedef __bf16 bf16x4 __attribute__((ext_vector_type(4)));
typedef __bf16 bf16x8 __attribute__((ext_vector_type(8)));
typedef float f32x4 __attribute__((ext_vector_type(4)));

// global -> LDS direct copy, 16B per lane. LDS dest must be lane-contiguous.
__device__ __forceinline__ void gld_lds16(const void* g, void* l) {
  __builtin_amdgcn_global_load_lds(
      (const __attribute__((address_space(1))) void*)(uintptr_t)g,
      (__attribute__((address_space(3))) void*)(uint32_t)(uintptr_t)l,
      16, 0, 0);
}

// ---------------------------------------------------------------------------
// Kernel 1: gating (fp32 exact) + per-token choice write + x fp32->bf16.
// One wave per token. No atomics (round-1 lesson: contended global atomics
// cost ~200us across 8 XCDs).
// ---------------------------------------------------------------------------
__global__ __launch_bounds__(256) void gate_route_kernel(
    const float* __restrict__ x, const float* __restrict__ gw,
    bf16* __restrict__ xbf, int* __restrict__ echoice, float* __restrict__ pchoice)
{
  const int wid  = threadIdx.x >> 6;
  const int lane = threadIdx.x & 63;
  const int t = blockIdx.x * 4 + wid;   // grid = 2048 -> t in [0, 8192)

  const float* xrow = x + (size_t)t * HIDDEN;
  bf16* xbrow = xbf + (size_t)t * HIDDEN;

  float acc[NEXP];
#pragma unroll
  for (int e = 0; e < NEXP; ++e) acc[e] = 0.f;

#pragma unroll
  for (int it = 0; it < 4; ++it) {
    const int idx = it * 256 + lane * 4;
    float4 xv = *(const float4*)(xrow + idx);
    bf16x4 xb;
    xb[0] = (bf16)xv.x; xb[1] = (bf16)xv.y; xb[2] = (bf16)xv.z; xb[3] = (bf16)xv.w;
    *(bf16x4*)(xbrow + idx) = xb;
#pragma unroll
    for (int e = 0; e < NEXP; ++e) {
      float4 gv = *(const float4*)(gw + e * HIDDEN + idx);
      acc[e] += xv.x * gv.x + xv.y * gv.y + xv.z * gv.z + xv.w * gv.w;
    }
  }
#pragma unroll
  for (int e = 0; e < NEXP; ++e) {
#pragma unroll
    for (int off = 32; off > 0; off >>= 1)
      acc[e] += __shfl_xor(acc[e], off, 64);
  }

  if (lane == 0) {
    float m = acc[0];
#pragma unroll
    for (int e = 1; e < NEXP; ++e) m = fmaxf(m, acc[e]);
    float p[NEXP]; float s = 0.f;
#pragma unroll
    for (int e = 0; e < NEXP; ++e) { p[e] = expf(acc[e] - m); s += p[e]; }
    const float inv = 1.f / s;
#pragma unroll
    for (int e = 0; e < NEXP; ++e) p[e] *= inv;
    // top-2, ties -> lower index (jax.lax.top_k semantics)
    int i0 = 0; float p0 = p[0];
#pragma unroll
    for (int e = 1; e < NEXP; ++e) if (p[e] > p0) { p0 = p[e]; i0 = e; }
    int i1 = -1; float p1 = -1.f;
#pragma unroll
    for (int e = 0; e < NEXP; ++e) if (e != i0 && p[e] > p1) { p1 = p[e]; i1 = e; }

    echoice[t]              = i0;
    echoice[NUM_TOKENS + t] = i1;
    pchoice[t]              = p0;
    pchoice[NUM_TOKENS + t] = p1;
  }
}

// ---------------------------------------------------------------------------
// Kernel 1b: DETERMINISTIC two-phase list compaction. ONE block, 1024 threads
// = 16 waves; 8 waves per top-k slot, 1024 tokens per wave. Each lane
// preloads its 16 chunk values (independent loads -> overlapped).
// Pass 1: ballot-count per (wave,expert) -> LDS; wave-offset prefix;
// Pass 2: ballot-rank scatter. No atomics; output order identical every
// launch (token-sorted).
// ---------------------------------------------------------------------------
__global__ __launch_bounds__(1024) void build_lists_kernel(
    const int* __restrict__ echoice, const float* __restrict__ pchoice,
    int* __restrict__ cnt, int* __restrict__ tok, float* __restrict__ wt)
{
  const int tid  = threadIdx.x;
  const int wave = tid >> 6;      // 0..15
  const int lane = tid & 63;
  const int k = wave >> 3;        // top-k slot 0/1
  const int w = wave & 7;         // wave within slot
  const int tbase = w * 1024;     // this wave's token range

  const int*   ec = echoice + k * NUM_TOKENS;
  const float* pc = pchoice + k * NUM_TOKENS;

  __shared__ int wcnt[2][8][NEXP];
  __shared__ int woff[2][8][NEXP];

  const unsigned long long lower = ((unsigned long long)1 << lane) - 1;

  // preload: 16 chunks of 64 tokens, all independent
  int   ev[16];
  float pv[16];
#pragma unroll
  for (int c = 0; c < 16; ++c) {
    ev[c] = ec[tbase + c * 64 + lane];
    pv[c] = pc[tbase + c * 64 + lane];
  }

  // pass 1: per-wave per-expert counts
  int cl[NEXP];
#pragma unroll
  for (int e = 0; e < NEXP; ++e) cl[e] = 0;
#pragma unroll
  for (int c = 0; c < 16; ++c) {
#pragma unroll
    for (int l = 0; l < NEXP; ++l)
      cl[l] += __popcll(__ballot(ev[c] == l));
  }
  if (lane < NEXP) wcnt[k][w][lane] = cl[lane];
  __syncthreads();

  // exclusive prefix over waves (8 adds, done by 8 lanes per slot-wave)
  if (lane < NEXP) {
    int off = 0;
#pragma unroll
    for (int ww = 0; ww < 8; ++ww) {
      if (ww == w) woff[k][w][lane] = off;
      off += wcnt[k][ww][lane];
    }
    if (w == 0) cnt[k * NEXP + lane] = off;   // total over all 8 waves
  }
  __syncthreads();

  // pass 2: ballot-rank scatter from this wave's offsets
  int run[NEXP];
#pragma unroll
  for (int e = 0; e < NEXP; ++e) run[e] = woff[k][w][e];
#pragma unroll
  for (int c = 0; c < 16; ++c) {
    const int e = ev[c];
    int pos = 0;
#pragma unroll
    for (int l = 0; l < NEXP; ++l) {
      const unsigned long long m = __ballot(ev[c] == l);
      if (e == l) pos = run[l] + __popcll(m & lower);
      run[l] += __popcll(m);
    }
    const int list = k * NEXP + e;
    tok[(size_t)list * NUM_TOKENS + pos] = tbase + c * 64 + lane;
    wt [(size_t)list * NUM_TOKENS + pos] = pv[c];
  }
}

// ---------------------------------------------------------------------------
// Kernel 2: expert weights fp32 -> bf16
// ---------------------------------------------------------------------------
__global__ __launch_bounds__(256) void convert_w_kernel(
    const float* __restrict__ w, bf16* __restrict__ wbf)
{
  const size_t i = ((size_t)blockIdx.x * 256 + threadIdx.x) * 4;
  float4 v = *(const float4*)(w + i);
  bf16x4 b;
  b[0] = (bf16)v.x; b[1] = (bf16)v.y; b[2] = (bf16)v.z; b[3] = (bf16)v.w;
  *(bf16x4*)(wbf + i) = b;
}

// ---------------------------------------------------------------------------
// Kernel 3: grouped GEMM, BOTH top-k slots fused in one launch (grid.z = 16).
// z -> (e = z>>1, k = z&1) so the two lists sharing expert e's weights are
// adjacent in dispatch order (L2/L3 weight reuse). Epilogue: native fp32
// atomicAdd into zero-initialized out. Each out element gets exactly 2
// contributions; fp32 add is commutative -> bitwise deterministic.
// 128x128 tile, BK=32, 4 waves of 4x4 mfma_f32_16x16x32_bf16 (m97 structure).
// Fusion doubles resident blocks (~2 -> ~4 per CU): the pass counters were
// latency-bound (MfmaUtil 14%, HBM 34%, Occ 16%), not roofline-bound.
// ---------------------------------------------------------------------------
__global__ __launch_bounds__(256) void moe_gemm_kernel(
    const bf16* __restrict__ xbf, const bf16* __restrict__ wbf,
    const int* __restrict__ cnt, const int* __restrict__ tok,
    const float* __restrict__ wt, float* __restrict__ out)
{
  const int e  = blockIdx.z >> 1;
  const int k  = blockIdx.z & 1;
  const int list = k * NEXP + e;
  const int mt = blockIdx.y;
  const int nt = blockIdx.x;
  const int count = cnt[list];
  const int m0 = mt * 128;
  if (m0 >= count) return;
  const int rows = min(128, count - m0);

  __shared__ __align__(16) bf16 As[128 * 32];
  __shared__ __align__(16) bf16 Bs[128 * 32];
  __shared__ int   tok_s[128];
  __shared__ float wt_s[128];

  const int tid = threadIdx.x;
  if (tid < 128) {
    if (tid < rows) {
      tok_s[tid] = tok[(size_t)list * NUM_TOKENS + m0 + tid];
      wt_s[tid]  = wt [(size_t)list * NUM_TOKENS + m0 + tid];
    } else { tok_s[tid] = 0; wt_s[tid] = 0.f; }
  }
  __syncthreads();

  // staging: thread -> (row = tid/4, 8-elem chunk = tid%4); lds dest = tid*16B
  const int rr = tid >> 2;
  const int c8 = tid & 3;
  const bf16* gA0 = xbf + (size_t)tok_s[rr] * HIDDEN + c8 * 8;
  const bf16* gA1 = xbf + (size_t)tok_s[64 + rr] * HIDDEN + c8 * 8;
  const bf16* gB0 = wbf + (size_t)e * HIDDEN * HIDDEN
                  + (size_t)(nt * 128 + rr) * HIDDEN + c8 * 8;
  const bf16* gB1 = gB0 + (size_t)64 * HIDDEN;
  bf16* lA = As + tid * 8;
  bf16* lB = Bs + tid * 8;

  const int wid  = tid >> 6;
  const int lane = tid & 63;
  const int wm = (wid >> 1) * 64;
  const int wn = (wid & 1) * 64;
  const int qm = lane & 15;          // m (or n) within 16
  const int q8 = (lane >> 4) * 8;    // k chunk base within 32

  f32x4 acc[4][4];
#pragma unroll
  for (int i = 0; i < 4; ++i)
#pragma unroll
    for (int j = 0; j < 4; ++j) acc[i][j] = (f32x4){0.f, 0.f, 0.f, 0.f};

  for (int kc = 0; kc < HIDDEN; kc += 32) {
    gld_lds16(gA0 + kc, lA);
    gld_lds16(gA1 + kc, lA + 64 * 32);
    gld_lds16(gB0 + kc, lB);
    gld_lds16(gB1 + kc, lB + 64 * 32);
    __syncthreads();

    bf16x8 a[4], b[4];
#pragma unroll
    for (int i = 0; i < 4; ++i)
      a[i] = *(const bf16x8*)(As + (wm + i * 16 + qm) * 32 + q8);
#pragma unroll
    for (int j = 0; j < 4; ++j)
      b[j] = *(const bf16x8*)(Bs + (wn + j * 16 + qm) * 32 + q8);
#pragma unroll
    for (int i = 0; i < 4; ++i)
#pragma unroll
      for (int j = 0; j < 4; ++j)
        acc[i][j] = __builtin_amdgcn_mfma_f32_16x16x32_bf16(a[i], b[j], acc[i][j], 0, 0, 0);
    __syncthreads();
  }

  // epilogue: C/D layout col=lane&15, row=(lane>>4)*4+reg  (m89-verified)
  const int h0 = nt * 128 + wn + (lane & 15);
#pragma unroll
  for (int i = 0; i < 4; ++i) {
    const int rbase = wm + i * 16 + (lane >> 4) * 4;
#pragma unroll
    for (int r = 0; r < 4; ++r) {
      const int rl = rbase + r;
      if (rl < rows) {
        const int t = tok_s[rl];
        const float w = wt_s[rl];
        float* orow = out + (size_t)t * HIDDEN + h0;
#pragma unroll
        for (int j = 0; j < 4; ++j) {
          const float v = w * acc[i][j][r];
          unsafeAtomicAdd(orow + j * 16, v);   // native global_atomic_add_f32
        }
      }
    }
  }
}

// ---------------------------------------------------------------------------
extern "C" void kernel_launch(void* const* d_in, const int* in_sizes, int n_in,
                              void* d_out, int out_size, void* d_ws, size_t ws_size,
                              hipStream_t stream) {
  const float* x  = (const float*)d_in[0];
  const float* gw = (const float*)d_in[1];
  const float* ew = (const float*)d_in[2];
  float* out = (float*)d_out;

  // ws layout
  char* ws = (char*)d_ws;
  int*   cnt     = (int*)ws;                                           // 16 ints
  int*   echoice = (int*)(ws + 256);                                   // 2*8192 ints
  float* pchoice = (float*)(ws + 256 + (size_t)2 * NUM_TOKENS * 4);    // 2*8192 f32
  int*   tok = (int*)(ws + 256 + (size_t)4 * NUM_TOKENS * 4);          // 16*8192 ints
  float* wt  = (float*)(ws + 256 + (size_t)20 * NUM_TOKENS * 4);       // 16*8192 f32
  bf16*  xbf = (bf16*)(ws + 256 + (size_t)36 * NUM_TOKENS * 4);        // 16MB
  bf16*  wbf = (bf16*)((char*)xbf + (size_t)NUM_TOKENS * HIDDEN * 2);  // 16MB

  // zero-init out for the atomic epilogue (stream-ordered, capture-safe)
  hipMemsetAsync(out, 0, (size_t)NUM_TOKENS * HIDDEN * sizeof(float), stream);

  gate_route_kernel<<<NUM_TOKENS / 4, 256, 0, stream>>>(x, gw, xbf, echoice, pchoice);
  build_lists_kernel<<<1, 1024, 0, stream>>>(echoice, pchoice, cnt, tok, wt);
  convert_w_kernel<<<(NEXP * HIDDEN * HIDDEN) / (4 * 256), 256, 0, stream>>>(ew, wbf);

  dim3 grid(HIDDEN / 128, NUM_TOKENS / 128, 2 * NEXP);
  moe_gemm_kernel<<<grid, 256, 0, stream>>>(xbf, wbf, cnt, tok, wt, out);
}

// Round 2
// 210.097 us; speedup vs baseline: 1.1089x; 1.1089x over previous
//
#include <hip/hip_runtime.h>
#include <hip/hip_bf16.h>
#include <stdint.h>

#define NUM_TOKENS 8192
#define HIDDEN 1024
#define NEXP 8
#define TOPK 2

typedef __bf16 bf16;
typedef __bf16 bf16x4 __attribute__((ext_vector_type(4)));
typedef __bf16 bf16x8 __attribute__((ext_vector_type(8)));
typedef float f32x4 __attribute__((ext_vector_type(4)));

// global -> LDS direct copy, 16B per lane. LDS dest must be lane-contiguous.
__device__ __forceinline__ void gld_lds16(const void* g, void* l) {
  __builtin_amdgcn_global_load_lds(
      (const __attribute__((address_space(1))) void*)(uintptr_t)g,
      (__attribute__((address_space(3))) void*)(uint32_t)(uintptr_t)l,
      16, 0, 0);
}

// ---------------------------------------------------------------------------
// Kernel 1: gating (fp32 exact) + per-token choice write + x fp32->bf16.
// One wave per token.
// ---------------------------------------------------------------------------
__global__ __launch_bounds__(256) void gate_route_kernel(
    const float* __restrict__ x, const float* __restrict__ gw,
    bf16* __restrict__ xbf, int* __restrict__ echoice, float* __restrict__ pchoice)
{
  const int wid  = threadIdx.x >> 6;
  const int lane = threadIdx.x & 63;
  const int t = blockIdx.x * 4 + wid;   // grid = 2048 -> t in [0, 8192)

  const float* xrow = x + (size_t)t * HIDDEN;
  bf16* xbrow = xbf + (size_t)t * HIDDEN;

  float acc[NEXP];
#pragma unroll
  for (int e = 0; e < NEXP; ++e) acc[e] = 0.f;

#pragma unroll
  for (int it = 0; it < 4; ++it) {
    const int idx = it * 256 + lane * 4;
    float4 xv = *(const float4*)(xrow + idx);
    bf16x4 xb;
    xb[0] = (bf16)xv.x; xb[1] = (bf16)xv.y; xb[2] = (bf16)xv.z; xb[3] = (bf16)xv.w;
    *(bf16x4*)(xbrow + idx) = xb;
#pragma unroll
    for (int e = 0; e < NEXP; ++e) {
      float4 gv = *(const float4*)(gw + e * HIDDEN + idx);
      acc[e] += xv.x * gv.x + xv.y * gv.y + xv.z * gv.z + xv.w * gv.w;
    }
  }
#pragma unroll
  for (int e = 0; e < NEXP; ++e) {
#pragma unroll
    for (int off = 32; off > 0; off >>= 1)
      acc[e] += __shfl_xor(acc[e], off, 64);
  }

  if (lane == 0) {
    float m = acc[0];
#pragma unroll
    for (int e = 1; e < NEXP; ++e) m = fmaxf(m, acc[e]);
    float p[NEXP]; float s = 0.f;
#pragma unroll
    for (int e = 0; e < NEXP; ++e) { p[e] = expf(acc[e] - m); s += p[e]; }
    const float inv = 1.f / s;
#pragma unroll
    for (int e = 0; e < NEXP; ++e) p[e] *= inv;
    // top-2, ties -> lower index (jax.lax.top_k semantics)
    int i0 = 0; float p0 = p[0];
#pragma unroll
    for (int e = 1; e < NEXP; ++e) if (p[e] > p0) { p0 = p[e]; i0 = e; }
    int i1 = -1; float p1 = -1.f;
#pragma unroll
    for (int e = 0; e < NEXP; ++e) if (e != i0 && p[e] > p1) { p1 = p[e]; i1 = e; }

    echoice[t]              = i0;
    echoice[NUM_TOKENS + t] = i1;
    pchoice[t]              = p0;
    pchoice[NUM_TOKENS + t] = p1;
  }
}

// ---------------------------------------------------------------------------
// Kernel 1b: DETERMINISTIC compaction, now 16 BLOCKS (one per (k,expert)
// list) instead of 1 block -- the single-block version serialized on one CU.
// Each block: 16 waves x 512 tokens, ballot-count -> LDS wave-prefix ->
// ballot-rank scatter. Output is token-sorted: bit-identical to the
// previous verified single-block version.
// ---------------------------------------------------------------------------
__global__ __launch_bounds__(1024) void build_lists_kernel(
    const int* __restrict__ echoice, const float* __restrict__ pchoice,
    int* __restrict__ cnt, int* __restrict__ tok, float* __restrict__ wt)
{
  const int list = blockIdx.x;         // 0..15
  const int k = list >> 3;
  const int e = list & 7;
  const int tid  = threadIdx.x;
  const int wave = tid >> 6;           // 0..15
  const int lane = tid & 63;
  const int tbase = wave * 512;

  const int*   ec = echoice + k * NUM_TOKENS;
  const float* pc = pchoice + k * NUM_TOKENS;

  __shared__ int wcnt[16];
  __shared__ int woff[16];

  const unsigned long long lower = ((unsigned long long)1 << lane) - 1;

  int   ev[8];
  float pv[8];
#pragma unroll
  for (int c = 0; c < 8; ++c) {
    ev[c] = ec[tbase + c * 64 + lane];
    pv[c] = pc[tbase + c * 64 + lane];
  }
  unsigned long long m[8];
  int cl = 0;
#pragma unroll
  for (int c = 0; c < 8; ++c) { m[c] = __ballot(ev[c] == e); cl += __popcll(m[c]); }
  if (lane == 0) wcnt[wave] = cl;
  __syncthreads();
  if (tid == 0) {
    int off = 0;
#pragma unroll
    for (int w = 0; w < 16; ++w) { woff[w] = off; off += wcnt[w]; }
    cnt[list] = off;
  }
  __syncthreads();
  int run = woff[wave];
#pragma unroll
  for (int c = 0; c < 8; ++c) {
    if (ev[c] == e) {
      const int pos = run + __popcll(m[c] & lower);
      tok[(size_t)list * NUM_TOKENS + pos] = tbase + c * 64 + lane;
      wt [(size_t)list * NUM_TOKENS + pos] = pv[c];
    }
    run += __popcll(m[c]);
  }
}

// ---------------------------------------------------------------------------
// Kernel 2: expert weights fp32 -> bf16
// ---------------------------------------------------------------------------
__global__ __launch_bounds__(256) void convert_w_kernel(
    const float* __restrict__ w, bf16* __restrict__ wbf)
{
  const size_t i = ((size_t)blockIdx.x * 256 + threadIdx.x) * 4;
  float4 v = *(const float4*)(w + i);
  bf16x4 b;
  b[0] = (bf16)v.x; b[1] = (bf16)v.y; b[2] = (bf16)v.z; b[3] = (bf16)v.w;
  *(bf16x4*)(wbf + i) = b;
}

// ---------------------------------------------------------------------------
// Kernel 3: grouped GEMM, both top-k slots in one launch (grid.z = 16).
// Round-1 lesson: per-block K-loop was serially latency-bound (stage ->
// vmcnt(0) drain -> compute: MfmaUtil 14%, everything idle). New structure:
//   - BK=64, double-buffered LDS (2x16KB A + 2x16KB B = 64KB, 2 blocks/CU)
//   - 2-phase prefetch (T3-minimum): issue global_load_lds for tile t+1
//     BEFORE ds_read+MFMA of tile t; ONE __syncthreads() per K-step whose
//     vmcnt(0) drain lands after ~full compute phase of cover.
//   - T2 XOR swizzle: [128][64] bf16 rows are 128B = exact 32-bank stride
//     (16-way conflict). physChunk16B = logicalChunk ^ (row&7) (involution).
//     global_load_lds writes linearly, so the SOURCE address carries the
//     inverse permutation (rule #21); ds_read applies the same XOR.
//     -> 2-way (free, m136).
// Epilogue: native fp32 atomicAdd into zeroed out; exactly 2 contributions
// per element; fp32 add commutative -> deterministic.
// ---------------------------------------------------------------------------
__global__ __launch_bounds__(256) void moe_gemm_kernel(
    const bf16* __restrict__ xbf, const bf16* __restrict__ wbf,
    const int* __restrict__ cnt, const int* __restrict__ tok,
    const float* __restrict__ wt, float* __restrict__ out)
{
  const int e  = blockIdx.z >> 1;
  const int k  = blockIdx.z & 1;
  const int list = k * NEXP + e;
  const int mt = blockIdx.y;
  const int nt = blockIdx.x;
  const int count = cnt[list];
  const int m0 = mt * 128;
  if (m0 >= count) return;
  const int rows = min(128, count - m0);

  __shared__ __align__(16) bf16 As[2 * 128 * 64];
  __shared__ __align__(16) bf16 Bs[2 * 128 * 64];
  __shared__ int   tok_s[128];
  __shared__ float wt_s[128];

  const int tid = threadIdx.x;
  if (tid < 128) {
    if (tid < rows) {
      tok_s[tid] = tok[(size_t)list * NUM_TOKENS + m0 + tid];
      wt_s[tid]  = wt [(size_t)list * NUM_TOKENS + m0 + tid];
    } else { tok_s[tid] = 0; wt_s[tid] = 0.f; }
  }
  __syncthreads();

  // staging geometry: thread -> (rowInPass = tid>>3, physChunk = tid&7);
  // 4 passes of 32 rows each cover 128 rows. LDS dest is LINEAR
  // (p*2048 + tid*8 elems); the source chunk is the inverse-swizzled one:
  // logicalChunk = physChunk ^ (row&7), and row&7 == (tid>>3)&7 for all p.
  const int csrc = (tid & 7) ^ ((tid >> 3) & 7);
  const bf16* aptr[4];
  const bf16* bptr[4];
  const size_t eoff = (size_t)e * HIDDEN * HIDDEN;
#pragma unroll
  for (int p = 0; p < 4; ++p) {
    const int r = p * 32 + (tid >> 3);
    aptr[p] = xbf + (size_t)tok_s[r] * HIDDEN + csrc * 8;
    bptr[p] = wbf + eoff + (size_t)(nt * 128 + r) * HIDDEN + csrc * 8;
  }
  bf16* la = As + tid * 8;
  bf16* lb = Bs + tid * 8;

  const int wid  = tid >> 6;
  const int lane = tid & 63;
  const int wm = (wid >> 1) * 64;
  const int wn = (wid & 1) * 64;
  const int qm = lane & 15;          // m (or n) within 16
  const int l4 = lane >> 4;          // 8-elem k-subchunk within 32

  f32x4 acc[4][4];
#pragma unroll
  for (int i = 0; i < 4; ++i)
#pragma unroll
    for (int j = 0; j < 4; ++j) acc[i][j] = (f32x4){0.f, 0.f, 0.f, 0.f};

  // prologue: stage K-tile 0 into buffer 0, full drain once.
#pragma unroll
  for (int p = 0; p < 4; ++p) {
    gld_lds16(aptr[p], la + p * 2048);
    gld_lds16(bptr[p], lb + p * 2048);
  }
  __syncthreads();

  for (int t = 0; t < 16; ++t) {
    const int cur = t & 1;
    // issue next tile's loads FIRST -- they fly while we compute.
    if (t < 15) {
      const int kc = (t + 1) * 64;
      bf16* lan = la + (cur ^ 1) * 8192;
      bf16* lbn = lb + (cur ^ 1) * 8192;
#pragma unroll
      for (int p = 0; p < 4; ++p) {
        gld_lds16(aptr[p] + kc, lan + p * 2048);
        gld_lds16(bptr[p] + kc, lbn + p * 2048);
      }
    }

    const bf16* Ab = As + cur * 8192;
    const bf16* Bb = Bs + cur * 8192;
    bf16x8 a[4][2], b[4][2];
#pragma unroll
    for (int i = 0; i < 4; ++i) {
      const int r = wm + i * 16 + qm;
      const int x7 = r & 7;
      a[i][0] = *(const bf16x8*)(Ab + r * 64 + (l4 ^ x7) * 8);
      a[i][1] = *(const bf16x8*)(Ab + r * 64 + ((4 + l4) ^ x7) * 8);
    }
#pragma unroll
    for (int j = 0; j < 4; ++j) {
      const int r = wn + j * 16 + qm;
      const int x7 = r & 7;
      b[j][0] = *(const bf16x8*)(Bb + r * 64 + (l4 ^ x7) * 8);
      b[j][1] = *(const bf16x8*)(Bb + r * 64 + ((4 + l4) ^ x7) * 8);
    }
#pragma unroll
    for (int h = 0; h < 2; ++h)
#pragma unroll
      for (int i = 0; i < 4; ++i)
#pragma unroll
        for (int j = 0; j < 4; ++j)
          acc[i][j] = __builtin_amdgcn_mfma_f32_16x16x32_bf16(a[i][h], b[j][h], acc[i][j], 0, 0, 0);

    // one barrier per K-step: its vmcnt(0) drain waits on the PREFETCHED
    // tile, issued ~a full compute phase ago; also fences buffer reuse.
    if (t < 15) __syncthreads();
  }

  // epilogue: C/D layout col=lane&15, row=(lane>>4)*4+reg  (m89-verified)
  const int h0 = nt * 128 + wn + (lane & 15);
#pragma unroll
  for (int i = 0; i < 4; ++i) {
    const int rbase = wm + i * 16 + (lane >> 4) * 4;
#pragma unroll
    for (int r = 0; r < 4; ++r) {
      const int rl = rbase + r;
      if (rl < rows) {
        const int t = tok_s[rl];
        const float w = wt_s[rl];
        float* orow = out + (size_t)t * HIDDEN + h0;
#pragma unroll
        for (int j = 0; j < 4; ++j) {
          const float v = w * acc[i][j][r];
          unsafeAtomicAdd(orow + j * 16, v);   // native global_atomic_add_f32
        }
      }
    }
  }
}

// ---------------------------------------------------------------------------
extern "C" void kernel_launch(void* const* d_in, const int* in_sizes, int n_in,
                              void* d_out, int out_size, void* d_ws, size_t ws_size,
                              hipStream_t stream) {
  const float* x  = (const float*)d_in[0];
  const float* gw = (const float*)d_in[1];
  const float* ew = (const float*)d_in[2];
  float* out = (float*)d_out;

  // ws layout
  char* ws = (char*)d_ws;
  int*   cnt     = (int*)ws;                                           // 16 ints
  int*   echoice = (int*)(ws + 256);                                   // 2*8192 ints
  float* pchoice = (float*)(ws + 256 + (size_t)2 * NUM_TOKENS * 4);    // 2*8192 f32
  int*   tok = (int*)(ws + 256 + (size_t)4 * NUM_TOKENS * 4);          // 16*8192 ints
  float* wt  = (float*)(ws + 256 + (size_t)20 * NUM_TOKENS * 4);       // 16*8192 f32
  bf16*  xbf = (bf16*)(ws + 256 + (size_t)36 * NUM_TOKENS * 4);        // 16MB
  bf16*  wbf = (bf16*)((char*)xbf + (size_t)NUM_TOKENS * HIDDEN * 2);  // 16MB

  // zero-init out for the atomic epilogue (stream-ordered, capture-safe)
  hipMemsetAsync(out, 0, (size_t)NUM_TOKENS * HIDDEN * sizeof(float), stream);

  gate_route_kernel<<<NUM_TOKENS / 4, 256, 0, stream>>>(x, gw, xbf, echoice, pchoice);
  build_lists_kernel<<<2 * NEXP, 1024, 0, stream>>>(echoice, pchoice, cnt, tok, wt);
  convert_w_kernel<<<(NEXP * HIDDEN * HIDDEN) / (4 * 256), 256, 0, stream>>>(ew, wbf);

  dim3 grid(HIDDEN / 128, NUM_TOKENS / 128, 2 * NEXP);
  moe_gemm_kernel<<<grid, 256, 0, stream>>>(xbf, wbf, cnt, tok, wt, out);
}

// Round 3
// 204.653 us; speedup vs baseline: 1.1384x; 1.0266x over previous
//
#include <hip/hip_runtime.h>
#include <hip/hip_bf16.h>
#include <stdint.h>

#define NUM_TOKENS 8192
#define HIDDEN 1024
#define NEXP 8
#define TOPK 2

typedef __bf16 bf16;
typedef __bf16 bf16x4 __attribute__((ext_vector_type(4)));
typedef __bf16 bf16x8 __attribute__((ext_vector_type(8)));
typedef float f32x4 __attribute__((ext_vector_type(4)));

// global -> LDS direct copy, 16B per lane. LDS dest must be lane-contiguous.
__device__ __forceinline__ void gld_lds16(const void* g, void* l) {
  __builtin_amdgcn_global_load_lds(
      (const __attribute__((address_space(1))) void*)(uintptr_t)g,
      (__attribute__((address_space(3))) void*)(uint32_t)(uintptr_t)l,
      16, 0, 0);
}

// ---------------------------------------------------------------------------
// Kernel 1 "prep": THREE independent jobs fused into one launch (round-3
// lesson: each launch costs ~18us fixed overhead; 5 launches -> 3 saves
// ~36us and overlaps the BW of all three jobs).
//   blocks [0,2048):    gating (fp32 exact) + x fp32->bf16     (one wave/token)
//   blocks [2048,4096): expert weights fp32->bf16              (16 elem/thread)
//   blocks [4096,6144): zero out                                (16 f32/thread)
// No block-level barriers anywhere -> divergent block roles are safe.
// ---------------------------------------------------------------------------
__global__ __launch_bounds__(256) void prep_kernel(
    const float* __restrict__ x, const float* __restrict__ gw,
    const float* __restrict__ ew,
    bf16* __restrict__ xbf, bf16* __restrict__ wbf,
    int* __restrict__ echoice, float* __restrict__ pchoice,
    float* __restrict__ out)
{
  const int b   = blockIdx.x;
  const int tid = threadIdx.x;

  if (b < 2048) {
    // ---- gating + xbf ----
    const int wid  = tid >> 6;
    const int lane = tid & 63;
    const int t = b * 4 + wid;   // t in [0, 8192)

    const float* xrow = x + (size_t)t * HIDDEN;
    bf16* xbrow = xbf + (size_t)t * HIDDEN;

    float acc[NEXP];
#pragma unroll
    for (int e = 0; e < NEXP; ++e) acc[e] = 0.f;

#pragma unroll
    for (int it = 0; it < 4; ++it) {
      const int idx = it * 256 + lane * 4;
      float4 xv = *(const float4*)(xrow + idx);
      bf16x4 xb;
      xb[0] = (bf16)xv.x; xb[1] = (bf16)xv.y; xb[2] = (bf16)xv.z; xb[3] = (bf16)xv.w;
      *(bf16x4*)(xbrow + idx) = xb;
#pragma unroll
      for (int e = 0; e < NEXP; ++e) {
        float4 gv = *(const float4*)(gw + e * HIDDEN + idx);
        acc[e] += xv.x * gv.x + xv.y * gv.y + xv.z * gv.z + xv.w * gv.w;
      }
    }
#pragma unroll
    for (int e = 0; e < NEXP; ++e) {
#pragma unroll
      for (int off = 32; off > 0; off >>= 1)
        acc[e] += __shfl_xor(acc[e], off, 64);
    }

    if (lane == 0) {
      float m = acc[0];
#pragma unroll
      for (int e = 1; e < NEXP; ++e) m = fmaxf(m, acc[e]);
      float p[NEXP]; float s = 0.f;
#pragma unroll
      for (int e = 0; e < NEXP; ++e) { p[e] = expf(acc[e] - m); s += p[e]; }
      const float inv = 1.f / s;
#pragma unroll
      for (int e = 0; e < NEXP; ++e) p[e] *= inv;
      // top-2, ties -> lower index (jax.lax.top_k semantics)
      int i0 = 0; float p0 = p[0];
#pragma unroll
      for (int e = 1; e < NEXP; ++e) if (p[e] > p0) { p0 = p[e]; i0 = e; }
      int i1 = -1; float p1 = -1.f;
#pragma unroll
      for (int e = 0; e < NEXP; ++e) if (e != i0 && p[e] > p1) { p1 = p[e]; i1 = e; }

      echoice[t]              = i0;
      echoice[NUM_TOKENS + t] = i1;
      pchoice[t]              = p0;
      pchoice[NUM_TOKENS + t] = p1;
    }
  } else if (b < 4096) {
    // ---- expert weights fp32 -> bf16, 16 elems/thread ----
    const size_t i = ((size_t)(b - 2048) * 256 + tid) * 16;
    float4 v0 = *(const float4*)(ew + i);
    float4 v1 = *(const float4*)(ew + i + 4);
    float4 v2 = *(const float4*)(ew + i + 8);
    float4 v3 = *(const float4*)(ew + i + 12);
    bf16x8 o0, o1;
    o0[0] = (bf16)v0.x; o0[1] = (bf16)v0.y; o0[2] = (bf16)v0.z; o0[3] = (bf16)v0.w;
    o0[4] = (bf16)v1.x; o0[5] = (bf16)v1.y; o0[6] = (bf16)v1.z; o0[7] = (bf16)v1.w;
    o1[0] = (bf16)v2.x; o1[1] = (bf16)v2.y; o1[2] = (bf16)v2.z; o1[3] = (bf16)v2.w;
    o1[4] = (bf16)v3.x; o1[5] = (bf16)v3.y; o1[6] = (bf16)v3.z; o1[7] = (bf16)v3.w;
    *(bf16x8*)(wbf + i)     = o0;
    *(bf16x8*)(wbf + i + 8) = o1;
  } else {
    // ---- zero out (for the atomic GEMM epilogue), 16 f32/thread ----
    const size_t i = ((size_t)(b - 4096) * 256 + tid) * 16;
    const float4 z = {0.f, 0.f, 0.f, 0.f};
    *(float4*)(out + i)      = z;
    *(float4*)(out + i + 4)  = z;
    *(float4*)(out + i + 8)  = z;
    *(float4*)(out + i + 12) = z;
  }
}

// ---------------------------------------------------------------------------
// Kernel 1b: DETERMINISTIC compaction, 16 blocks (one per (k,expert) list).
// Each block: 16 waves x 512 tokens, ballot-count -> LDS wave-prefix ->
// ballot-rank scatter. Output is token-sorted (deterministic).
// ---------------------------------------------------------------------------
__global__ __launch_bounds__(1024) void build_lists_kernel(
    const int* __restrict__ echoice, const float* __restrict__ pchoice,
    int* __restrict__ cnt, int* __restrict__ tok, float* __restrict__ wt)
{
  const int list = blockIdx.x;         // 0..15
  const int k = list >> 3;
  const int e = list & 7;
  const int tid  = threadIdx.x;
  const int wave = tid >> 6;           // 0..15
  const int lane = tid & 63;
  const int tbase = wave * 512;

  const int*   ec = echoice + k * NUM_TOKENS;
  const float* pc = pchoice + k * NUM_TOKENS;

  __shared__ int wcnt[16];
  __shared__ int woff[16];

  const unsigned long long lower = ((unsigned long long)1 << lane) - 1;

  int   ev[8];
  float pv[8];
#pragma unroll
  for (int c = 0; c < 8; ++c) {
    ev[c] = ec[tbase + c * 64 + lane];
    pv[c] = pc[tbase + c * 64 + lane];
  }
  unsigned long long m[8];
  int cl = 0;
#pragma unroll
  for (int c = 0; c < 8; ++c) { m[c] = __ballot(ev[c] == e); cl += __popcll(m[c]); }
  if (lane == 0) wcnt[wave] = cl;
  __syncthreads();
  if (tid == 0) {
    int off = 0;
#pragma unroll
    for (int w = 0; w < 16; ++w) { woff[w] = off; off += wcnt[w]; }
    cnt[list] = off;
  }
  __syncthreads();
  int run = woff[wave];
#pragma unroll
  for (int c = 0; c < 8; ++c) {
    if (ev[c] == e) {
      const int pos = run + __popcll(m[c] & lower);
      tok[(size_t)list * NUM_TOKENS + pos] = tbase + c * 64 + lane;
      wt [(size_t)list * NUM_TOKENS + pos] = pv[c];
    }
    run += __popcll(m[c]);
  }
}

// ---------------------------------------------------------------------------
// Kernel 2: grouped GEMM, both top-k slots in one launch (grid.z = 16).
// Round-3 lesson: 2-buffer prefetch degenerates to vmcnt(0)-per-step (m131
// null). New: QUAD-buffered BK=32 pipeline, depth-3 prefetch, COUNTED
// vmcnt(8) at the per-step barrier -- 2 stages always in flight, never
// drained in the main loop (T4 mechanism).
// Safety argument:
//   - every wave issues identical load sequences -> vmcnt(8) retires that
//     wave's stage-t loads (oldest 4 of <=12 outstanding); the s_barrier
//     then proves ALL waves did -> buf[t] fully valid.
//   - STAGE(t+3) (overwriting buf[t-1]) is issued AFTER the barrier; all
//     reads of buf[t-1] were retired (lgkm wait before MFMA use) before the
//     issuing wave reached this barrier -> no WAR race.
// Swizzle for 64B rows: phys16B = l4 ^ ((row>>1)&3): bank-group start
// (16r + 4(l4^((r>>1)&3)))%32 hits all 8 groups over 8 rows -> 2-way (free).
// T5 setprio around the MFMA cluster (multi-buffer pipeline = role-split).
// Epilogue: native fp32 atomicAdd into zeroed out; exactly 2 contributions
// per element; fp32 add commutative -> deterministic.
// ---------------------------------------------------------------------------
__global__ __launch_bounds__(256) void moe_gemm_kernel(
    const bf16* __restrict__ xbf, const bf16* __restrict__ wbf,
    const int* __restrict__ cnt, const int* __restrict__ tok,
    const float* __restrict__ wt, float* __restrict__ out)
{
  const int e  = blockIdx.z >> 1;
  const int k  = blockIdx.z & 1;
  const int list = k * NEXP + e;
  const int mt = blockIdx.y;
  const int nt = blockIdx.x;
  const int count = cnt[list];
  const int m0 = mt * 128;
  if (m0 >= count) return;
  const int rows = min(128, count - m0);

  __shared__ __align__(16) bf16 As[4][128 * 32];   // 4 x 8KB
  __shared__ __align__(16) bf16 Bs[4][128 * 32];   // 4 x 8KB
  __shared__ int   tok_s[128];
  __shared__ float wt_s[128];

  const int tid = threadIdx.x;
  if (tid < 128) {
    if (tid < rows) {
      tok_s[tid] = tok[(size_t)list * NUM_TOKENS + m0 + tid];
      wt_s[tid]  = wt [(size_t)list * NUM_TOKENS + m0 + tid];
    } else { tok_s[tid] = 0; wt_s[tid] = 0.f; }
  }
  __syncthreads();

  // staging geometry: thread -> rows (tid>>2) and (tid>>2)+64, phys chunk
  // tid&3. LDS dest LINEAR (tid*16B, +2048 elems); source carries the
  // inverse swizzle: srcChunk = (tid&3) ^ ((row>>1)&3), identical for both
  // rows (64>>1 == 0 mod 4).
  const int csrc = (((tid & 3) ^ ((tid >> 3) & 3)) << 3);  // elems
  const int r0 = tid >> 2;
  const bf16* gA0 = xbf + (size_t)tok_s[r0] * HIDDEN + csrc;
  const bf16* gA1 = xbf + (size_t)tok_s[r0 + 64] * HIDDEN + csrc;
  const bf16* gB0 = wbf + (size_t)e * HIDDEN * HIDDEN
                  + (size_t)(nt * 128 + r0) * HIDDEN + csrc;
  const bf16* gB1 = gB0 + (size_t)64 * HIDDEN;

  auto STAGE = [&](int t, int buf) {
    const int kc = t << 5;
    bf16* la = &As[buf][0] + tid * 8;
    bf16* lb = &Bs[buf][0] + tid * 8;
    gld_lds16(gA0 + kc, la);
    gld_lds16(gA1 + kc, la + 2048);
    gld_lds16(gB0 + kc, lb);
    gld_lds16(gB1 + kc, lb + 2048);
  };

  const int wid  = tid >> 6;
  const int lane = tid & 63;
  const int wm = (wid >> 1) * 64;
  const int wn = (wid & 1) * 64;
  const int qm = lane & 15;          // m (or n) within 16
  const int l4 = lane >> 4;          // 8-elem k-chunk within 32

  f32x4 acc[4][4];
#pragma unroll
  for (int i = 0; i < 4; ++i)
#pragma unroll
    for (int j = 0; j < 4; ++j) acc[i][j] = (f32x4){0.f, 0.f, 0.f, 0.f};

  auto COMPUTE = [&](int buf) {
    const bf16* Ab = &As[buf][0];
    const bf16* Bb = &Bs[buf][0];
    bf16x8 a[4], b[4];
#pragma unroll
    for (int i = 0; i < 4; ++i) {
      const int r = wm + i * 16 + qm;
      a[i] = *(const bf16x8*)(Ab + r * 32 + ((l4 ^ ((r >> 1) & 3)) << 3));
    }
#pragma unroll
    for (int j = 0; j < 4; ++j) {
      const int r = wn + j * 16 + qm;
      b[j] = *(const bf16x8*)(Bb + r * 32 + ((l4 ^ ((r >> 1) & 3)) << 3));
    }
    __builtin_amdgcn_s_setprio(1);
#pragma unroll
    for (int i = 0; i < 4; ++i)
#pragma unroll
      for (int j = 0; j < 4; ++j)
        acc[i][j] = __builtin_amdgcn_mfma_f32_16x16x32_bf16(a[i], b[j], acc[i][j], 0, 0, 0);
    __builtin_amdgcn_s_setprio(0);
  };

  // prologue: 3 stages in flight (12 loads)
  STAGE(0, 0); STAGE(1, 1); STAGE(2, 2);

  // main loop: K=1024 -> 32 steps of BK=32; steady state keeps 2 stages
  // (8 loads) in flight across every barrier.
#pragma unroll 1
  for (int t = 0; t < 29; ++t) {
    asm volatile("s_waitcnt vmcnt(8)" ::: "memory");  // my stage-t loads done
    __builtin_amdgcn_s_barrier();                     // everyone's stage-t done
    STAGE(t + 3, (t + 3) & 3);                        // overwrite buf[t-1]
    COMPUTE(t & 3);
  }
  // tail: drain 8 -> 4 -> 0
  asm volatile("s_waitcnt vmcnt(8)" ::: "memory");
  __builtin_amdgcn_s_barrier();
  COMPUTE(1);                                          // t=29
  asm volatile("s_waitcnt vmcnt(4)" ::: "memory");
  __builtin_amdgcn_s_barrier();
  COMPUTE(2);                                          // t=30
  asm volatile("s_waitcnt vmcnt(0)" ::: "memory");
  __builtin_amdgcn_s_barrier();
  COMPUTE(3);                                          // t=31

  // epilogue: C/D layout col=lane&15, row=(lane>>4)*4+reg  (m89-verified)
  const int h0 = nt * 128 + wn + (lane & 15);
#pragma unroll
  for (int i = 0; i < 4; ++i) {
    const int rbase = wm + i * 16 + (lane >> 4) * 4;
#pragma unroll
    for (int r = 0; r < 4; ++r) {
      const int rl = rbase + r;
      if (rl < rows) {
        const int t = tok_s[rl];
        const float w = wt_s[rl];
        float* orow = out + (size_t)t * HIDDEN + h0;
#pragma unroll
        for (int j = 0; j < 4; ++j) {
          const float v = w * acc[i][j][r];
          unsafeAtomicAdd(orow + j * 16, v);   // native global_atomic_add_f32
        }
      }
    }
  }
}

// ---------------------------------------------------------------------------
extern "C" void kernel_launch(void* const* d_in, const int* in_sizes, int n_in,
                              void* d_out, int out_size, void* d_ws, size_t ws_size,
                              hipStream_t stream) {
  const float* x  = (const float*)d_in[0];
  const float* gw = (const float*)d_in[1];
  const float* ew = (const float*)d_in[2];
  float* out = (float*)d_out;

  // ws layout
  char* ws = (char*)d_ws;
  int*   cnt     = (int*)ws;                                           // 16 ints
  int*   echoice = (int*)(ws + 256);                                   // 2*8192 ints
  float* pchoice = (float*)(ws + 256 + (size_t)2 * NUM_TOKENS * 4);    // 2*8192 f32
  int*   tok = (int*)(ws + 256 + (size_t)4 * NUM_TOKENS * 4);          // 16*8192 ints
  float* wt  = (float*)(ws + 256 + (size_t)20 * NUM_TOKENS * 4);       // 16*8192 f32
  bf16*  xbf = (bf16*)(ws + 256 + (size_t)36 * NUM_TOKENS * 4);        // 16MB
  bf16*  wbf = (bf16*)((char*)xbf + (size_t)NUM_TOKENS * HIDDEN * 2);  // 16MB

  // 3 launches total (each launch ~18us fixed overhead -- round-3 finding)
  prep_kernel<<<6144, 256, 0, stream>>>(x, gw, ew, xbf, wbf, echoice, pchoice, out);
  build_lists_kernel<<<2 * NEXP, 1024, 0, stream>>>(echoice, pchoice, cnt, tok, wt);

  dim3 grid(HIDDEN / 128, NUM_TOKENS / 128, 2 * NEXP);
  moe_gemm_kernel<<<grid, 256, 0, stream>>>(xbf, wbf, cnt, tok, wt, out);
}